// Round 1
// baseline (173.753 us; speedup 1.0000x reference)
//
#include <hip/hip_runtime.h>
#include <hip/hip_bf16.h>

// VQ-EMA forward for z:(32,64,32,32) fp32, 1024 codes of dim 64.
// Outputs (flat, fp32): z_q (2097152) | loss (1) | counts (1024)

#define N_ROWS   32768      // 32*32*32
#define N_CODES  1024
#define EDIM     64
#define ZQ_ELEMS 2097152    // 32*64*32*32

// ---------------- kernel 1: per-code squared norms -------------------------
__global__ void vq_enorm(const float* __restrict__ emb, float* __restrict__ enorm) {
    int c = blockIdx.x * 256 + threadIdx.x;
    if (c < N_CODES) {
        float s = 0.f;
        #pragma unroll
        for (int k = 0; k < EDIM; ++k) {
            float v = emb[(c << 6) + k];
            s = fmaf(v, v, s);
        }
        enorm[c] = s;
    }
}

// ---------------- kernel 2: distance GEMM + argmin + fused counts/sums -----
// block = 256 threads, 512 blocks; block owns 64 consecutive rows.
__global__ __launch_bounds__(256, 2) void vq_dist(
        const float* __restrict__ z, const float* __restrict__ emb,
        const float* __restrict__ enorm,
        int* __restrict__ idx_out, float* __restrict__ counts,
        float* __restrict__ sums) {
    __shared__ float zT[64 * 68];      // zT[k][row], stride 68 (pad: conflict-free)
    __shared__ float eT[64 * 128];     // eT[k][code_local], stride 128
    __shared__ float znorm_s[64];
    __shared__ float enorm_s[128];
    __shared__ int   idx_s[64];

    const int t   = threadIdx.x;
    const int r0  = blockIdx.x * 64;   // first global row of this block
    const int b   = r0 >> 10;          // batch index (1024 rows per image)
    const int hw0 = r0 & 1023;

    // ---- stage z (transpose BCHW -> [k][row]); coalesced over rows ----
    {
        const int row = t & 63, q = t >> 6;
        #pragma unroll
        for (int i = 0; i < 16; ++i) {
            const int c = i * 4 + q;
            zT[c * 68 + row] = z[((b * 64 + c) << 10) + hw0 + row];
        }
    }
    __syncthreads();

    // ---- per-row ||z||^2 (sequential k, matches reference order) ----
    if (t < 64) {
        float s = 0.f;
        #pragma unroll
        for (int k = 0; k < EDIM; ++k) {
            const float v = zT[k * 68 + t];
            s = fmaf(v, v, s);
        }
        znorm_s[t] = s;
    }
    __syncthreads();

    const int tx = t & 15, ty = t >> 4;
    const int row0 = ty * 4;
    const int cA = tx * 4, cB = 64 + tx * 4;

    float zn[4];
    #pragma unroll
    for (int r = 0; r < 4; ++r) zn[r] = znorm_s[row0 + r];

    float best[4] = {INFINITY, INFINITY, INFINITY, INFINITY};
    int   bidx[4] = {0, 0, 0, 0};

    for (int ch = 0; ch < 8; ++ch) {
        // ---- stage 128 codes, transposed into eT[k][code_local] ----
        #pragma unroll
        for (int p = 0; p < 8; ++p) {
            const int li = p * 1024 + t * 4;
            const int cl = li >> 6, k4 = li & 63;
            const float4 v = *(const float4*)&emb[((ch * 128 + cl) << 6) + k4];
            eT[(k4 + 0) * 128 + cl] = v.x;
            eT[(k4 + 1) * 128 + cl] = v.y;
            eT[(k4 + 2) * 128 + cl] = v.z;
            eT[(k4 + 3) * 128 + cl] = v.w;
        }
        if (t < 128) enorm_s[t] = enorm[ch * 128 + t];
        __syncthreads();

        // ---- 4 rows x 8 codes register tile, K=64 sequential chain ----
        float acc[4][8];
        #pragma unroll
        for (int r = 0; r < 4; ++r)
            #pragma unroll
            for (int j = 0; j < 8; ++j) acc[r][j] = 0.f;

        #pragma unroll 4
        for (int k = 0; k < 64; ++k) {
            const float4 zv = *(const float4*)&zT[k * 68 + row0];
            const float4 ea = *(const float4*)&eT[k * 128 + cA];
            const float4 eb = *(const float4*)&eT[k * 128 + cB];
            const float za[4] = {zv.x, zv.y, zv.z, zv.w};
            const float e8[8] = {ea.x, ea.y, ea.z, ea.w, eb.x, eb.y, eb.z, eb.w};
            #pragma unroll
            for (int r = 0; r < 4; ++r)
                #pragma unroll
                for (int j = 0; j < 8; ++j)
                    acc[r][j] = fmaf(za[r], e8[j], acc[r][j]);
        }

        // ---- running argmin update (codes visited in increasing order) ----
        #pragma unroll
        for (int r = 0; r < 4; ++r) {
            #pragma unroll
            for (int j = 0; j < 8; ++j) {
                const int cl = (j < 4) ? (cA + j) : (cB + (j - 4));
                const float s = (zn[r] + enorm_s[cl]) - 2.0f * acc[r][j];
                if (s < best[r]) { best[r] = s; bidx[r] = ch * 128 + cl; }
            }
        }
        __syncthreads();   // protect eT before next chunk's staging
    }

    // ---- argmin reduce across the 16 threads sharing the same rows ----
    #pragma unroll
    for (int off = 1; off < 16; off <<= 1) {
        #pragma unroll
        for (int r = 0; r < 4; ++r) {
            const float os = __shfl_xor(best[r], off);
            const int   oi = __shfl_xor(bidx[r], off);
            if (os < best[r] || (os == best[r] && oi < bidx[r])) {
                best[r] = os; bidx[r] = oi;
            }
        }
    }
    if (tx == 0) {
        #pragma unroll
        for (int r = 0; r < 4; ++r) {
            const int row = row0 + r;
            idx_out[r0 + row] = bidx[r];
            atomicAdd(&counts[bidx[r]], 1.0f);
            idx_s[row] = bidx[r];
        }
    }
    __syncthreads();

    // ---- fused segment-sum scatter (z already in LDS) ----
    {
        const int k = t & 63, q = t >> 6;
        #pragma unroll
        for (int i = 0; i < 16; ++i) {
            const int row = i * 4 + q;
            atomicAdd(&sums[idx_s[row] * 64 + k], zT[k * 68 + row]);
        }
    }
}

// ---------------- kernel 3: EMA update -> new_embed; counts out; loss=0 ----
__global__ void vq_ema(const float* __restrict__ counts, const float* __restrict__ sums,
                       const float* __restrict__ cs, const float* __restrict__ csum,
                       float* __restrict__ new_embed, float* __restrict__ out_counts,
                       float* __restrict__ out_loss) {
    const int g = blockIdx.x * 256 + threadIdx.x;   // 0 .. 65535
    const int c = g >> 6, d = g & 63;
    const float cnt = counts[c];
    const float nsize = 0.99f * cs[c] + 0.01f * cnt;
    const float nsum  = 0.99f * csum[g] + 0.01f * sums[g];
    new_embed[g] = nsum / (nsize + 1e-5f);
    if (d == 0) out_counts[c] = cnt;
    if (g == 0) out_loss[0] = 0.f;
}

// ---------------- kernel 4: gather z_q, straight-through, loss -------------
__global__ __launch_bounds__(256) void vq_gather(
        const float* __restrict__ z, const int* __restrict__ idx,
        const float* __restrict__ new_embed,
        float* __restrict__ out_zq, float* __restrict__ out_loss) {
    __shared__ float red[4];
    const int t = threadIdx.x;
    const int r0 = blockIdx.x * 256;
    const int b  = r0 >> 10;
    const int hw = (r0 & 1023) + t;
    const int myidx = idx[r0 + t];

    float lsum = 0.f;
    #pragma unroll 8
    for (int c = 0; c < 64; ++c) {
        const float e  = new_embed[(myidx << 6) + c];
        const int  off = ((b * 64 + c) << 10) + hw;
        const float zv = z[off];
        const float diff = e - zv;             // z_q - zp (fp32, as reference)
        out_zq[off] = zv + diff;               // replicate straight-through rounding
        lsum = fmaf(diff, diff, lsum);
    }
    #pragma unroll
    for (int off = 32; off >= 1; off >>= 1) lsum += __shfl_down(lsum, off);
    if ((t & 63) == 0) red[t >> 6] = lsum;
    __syncthreads();
    if (t == 0) {
        const float s = red[0] + red[1] + red[2] + red[3];
        // BETA/count = 0.25 / 2^21 = 2^-23, exact in fp32
        atomicAdd(out_loss, s * (0.25f / 2097152.0f));
    }
}

// ---------------------------------------------------------------------------
extern "C" void kernel_launch(void* const* d_in, const int* in_sizes, int n_in,
                              void* d_out, int out_size, void* d_ws, size_t ws_size,
                              hipStream_t stream) {
    const float* z    = (const float*)d_in[0];   // (32,64,32,32)
    const float* emb  = (const float*)d_in[1];   // (1024,64)
    const float* cs   = (const float*)d_in[2];   // (1024,)
    const float* csum = (const float*)d_in[3];   // (1024,64)
    float* out = (float*)d_out;

    // ws layout (floats after the int idx area)
    int*   idx       = (int*)d_ws;                       // 32768 ints
    float* counts    = (float*)d_ws + 32768;             // 1024
    float* sums      = counts + 1024;                    // 65536
    float* enorm     = sums + 65536;                     // 1024
    float* new_embed = enorm + 1024;                     // 65536

    // zero the atomic accumulators (counts + sums), contiguous region
    hipMemsetAsync(counts, 0, (1024 + 65536) * sizeof(float), stream);

    vq_enorm<<<4, 256, 0, stream>>>(emb, enorm);
    vq_dist<<<512, 256, 0, stream>>>(z, emb, enorm, idx, counts, sums);
    vq_ema<<<256, 256, 0, stream>>>(counts, sums, cs, csum, new_embed,
                                    out + ZQ_ELEMS + 1,   // counts out
                                    out + ZQ_ELEMS);      // loss out (zeroed here)
    vq_gather<<<128, 256, 0, stream>>>(z, idx, new_embed, out, out + ZQ_ELEMS);
}